// Round 8
// baseline (717.655 us; speedup 1.0000x reference)
//
#include <hip/hip_runtime.h>
#include <cfloat>

#define NROWS 65536
#define DIM   256
#define KCB   4096

#define EPS_WIN  1.8e-4f
#define CAND_CAP 16

typedef __attribute__((ext_vector_type(8))) short short8;
typedef __attribute__((ext_vector_type(4))) float f32x4;

// ---------------- fp32 -> bf16 RNE ----------------
__device__ inline unsigned short f2bf(float x) {
  unsigned int u = __float_as_uint(x);
  return (unsigned short)((u + 0x7fffu + ((u >> 16) & 1u)) >> 16);
}

// ---------------- fused prep: bf16 convert + squared norms, one pass ----------------
__global__ void prep_norms_kernel(const float* __restrict__ z, const float* __restrict__ cb,
                                  unsigned short* __restrict__ zh, unsigned short* __restrict__ eh,
                                  float* __restrict__ znorm, float* __restrict__ enorm) {
  const int r    = blockIdx.x * 4 + (threadIdx.x >> 6);
  const int lane = threadIdx.x & 63;
  const float* src; unsigned short* dst; float* nrm; int row;
  if (r < NROWS) { src = z;  dst = zh; nrm = znorm; row = r; }
  else           { src = cb; dst = eh; nrm = enorm; row = r - NROWS; }
  const float4 v = ((const float4*)(src + (size_t)row * DIM))[lane];
  union { unsigned short us[4]; uint2 u2; } o;
  o.us[0] = f2bf(v.x); o.us[1] = f2bf(v.y); o.us[2] = f2bf(v.z); o.us[3] = f2bf(v.w);
  *(uint2*)(dst + (size_t)row * DIM + lane * 4) = o.u2;
  float s = v.x * v.x + v.y * v.y + v.z * v.z + v.w * v.w;
  #pragma unroll
  for (int off = 32; off > 0; off >>= 1) s += __shfl_down(s, off);
  if (lane == 0) nrm[row] = s;
}

// ---------------- MFMA screen: A-in-registers, whole-kt B staging ----------------
// Block: 128 rows x 128 codes/kt, 4 waves in 2x2 grid (wave = 64x64 quadrant).
// A fragments live in 128 VGPR full-depth (read once from LDS). Per kt: one
// 64KB B-tile staged via global_load_lds (linear LDS dest, inverse-swizzled
// per-lane global src), then 8 dc-groups of {4 ds_read_b128 + 16 MFMA}.
// 3 barriers/kt. Screen dist is SHIFTED: s = enorm[k] - 2*dot (argmin/window
// are shift-invariant per row; znorm not needed here).
__launch_bounds__(256, 2)
__global__ void screen_kernel(const unsigned short* __restrict__ zh,
                              const unsigned short* __restrict__ eh,
                              const float* __restrict__ enorm,
                              unsigned int* __restrict__ counts,
                              unsigned short* __restrict__ cands) {
  __shared__ __align__(16) unsigned short b_s[8][128][32];   // 64 KB, dc-chunked 64B rows
  __shared__ float tilemin_s[2][128];
  __shared__ unsigned int cnt_s[128];
  __shared__ unsigned short cand_s[128 * CAND_CAP];

  const int tid = threadIdx.x;
  const int wv  = tid >> 6;
  const int ln  = tid & 63;
  const int l15 = ln & 15;
  const int lg  = ln >> 4;
  const int wr  = wv >> 1;
  const int wc  = wv & 1;
  const int rbase = blockIdx.x * 128;

  if (tid < 128) cnt_s[tid] = 0u;

  unsigned short* bflat = &b_s[0][0][0];

  // ---- stage A tile (this block's 128 zh rows) into b_s (used as scratch) ----
  {
    const unsigned short* abase = zh + (size_t)rbase * DIM;
    #pragma unroll
    for (int i = 0; i < 16; ++i) {
      const int G  = i * 256 + wv * 64 + ln;          // linear 16B granule in LDS
      const int sw = G & 3, c = (G >> 2) & 127, dc = G >> 9;
      const int s4 = sw ^ ((c >> 1) & 3);             // inverse swizzle on SOURCE
      __builtin_amdgcn_global_load_lds(
          (const uint4*)(abase + (size_t)c * 256 + dc * 32 + s4 * 8),
          (uint4*)(bflat + (size_t)(i * 256 + wv * 64) * 8),
          16, 0, 0);
    }
  }
  __syncthreads();   // A landed (barrier drains vmcnt)

  // ---- A fragments -> registers, full depth (128 VGPR) ----
  short8 af[4][8];
  #pragma unroll
  for (int fr = 0; fr < 4; ++fr) {
    const int r  = wr * 64 + fr * 16 + l15;
    const int sl = lg ^ ((r >> 1) & 3);
    #pragma unroll
    for (int dc = 0; dc < 8; ++dc)
      af[fr][dc] = *(const short8*)(&b_s[dc][r][sl * 8]);
  }

  float rm[16];
  #pragma unroll
  for (int s = 0; s < 16; ++s) rm[s] = FLT_MAX;

  #pragma unroll 1
  for (int kt = 0; kt < KCB / 128; ++kt) {
    const int kcb0 = kt * 128;
    __syncthreads();   // prior b_s readers done (af loads on 1st iter; bf later)
    {
      const unsigned short* ebase = eh + (size_t)kcb0 * DIM;
      #pragma unroll
      for (int i = 0; i < 16; ++i) {
        const int G  = i * 256 + wv * 64 + ln;
        const int sw = G & 3, c = (G >> 2) & 127, dc = G >> 9;
        const int s4 = sw ^ ((c >> 1) & 3);
        __builtin_amdgcn_global_load_lds(
            (const uint4*)(ebase + (size_t)c * 256 + dc * 32 + s4 * 8),
            (uint4*)(bflat + (size_t)(i * 256 + wv * 64) * 8),
            16, 0, 0);
      }
    }
    __syncthreads();   // B tile landed

    f32x4 acc[4][4];
    #pragma unroll
    for (int fr = 0; fr < 4; ++fr)
      #pragma unroll
      for (int fc = 0; fc < 4; ++fc)
        acc[fr][fc] = (f32x4){0.f, 0.f, 0.f, 0.f};

    #pragma unroll
    for (int dc = 0; dc < 8; ++dc) {
      short8 bf[4];
      #pragma unroll
      for (int fc = 0; fc < 4; ++fc) {
        const int c  = wc * 64 + fc * 16 + l15;
        const int sw = lg ^ ((c >> 1) & 3);
        bf[fc] = *(const short8*)(&b_s[dc][c][sw * 8]);
      }
      #pragma unroll
      for (int fr = 0; fr < 4; ++fr)
        #pragma unroll
        for (int fc = 0; fc < 4; ++fc)
          acc[fr][fc] = __builtin_amdgcn_mfma_f32_16x16x32_bf16(
              af[fr][dc], bf[fc], acc[fr][fc], 0, 0, 0);
      __builtin_amdgcn_sched_barrier(0);   // stop bf hoisting across dc groups
    }

    // ---- epilogue: shifted dist, tile-min, cross-half share, window append ----
    float en_[4];
    #pragma unroll
    for (int fc = 0; fc < 4; ++fc) en_[fc] = enorm[kcb0 + wc * 64 + fc * 16 + l15];

    float tm[16];
    #pragma unroll
    for (int s = 0; s < 16; ++s) tm[s] = FLT_MAX;

    #pragma unroll
    for (int fr = 0; fr < 4; ++fr)
      #pragma unroll
      for (int fc = 0; fc < 4; ++fc)
        #pragma unroll
        for (int q = 0; q < 4; ++q) {
          const float d_ = fmaf(-2.0f, acc[fr][fc][q], en_[fc]);
          tm[fr * 4 + q] = fminf(tm[fr * 4 + q], d_);
        }

    #pragma unroll
    for (int s = 0; s < 16; ++s) {
      float v = tm[s];
      v = fminf(v, __shfl_xor(v, 1));
      v = fminf(v, __shfl_xor(v, 2));
      v = fminf(v, __shfl_xor(v, 4));
      v = fminf(v, __shfl_xor(v, 8));
      if (l15 == 0)
        tilemin_s[wc][wr * 64 + (s >> 2) * 16 + lg * 4 + (s & 3)] = v;
    }
    __syncthreads();   // tilemin halves visible

    float gmin = FLT_MAX;
    #pragma unroll
    for (int s = 0; s < 16; ++s) {
      const int rl = wr * 64 + (s >> 2) * 16 + lg * 4 + (s & 3);
      const float comb = fminf(tilemin_s[0][rl], tilemin_s[1][rl]);
      const float m = fminf(rm[s], comb);
      rm[s] = m;
      gmin = fminf(gmin, tm[s] - m);
    }

    if (__any(gmin <= EPS_WIN)) {
      #pragma unroll
      for (int fr = 0; fr < 4; ++fr)
        #pragma unroll
        for (int fc = 0; fc < 4; ++fc)
          #pragma unroll
          for (int q = 0; q < 4; ++q) {
            const float d_ = fmaf(-2.0f, acc[fr][fc][q], en_[fc]);
            if (d_ <= rm[fr * 4 + q] + EPS_WIN) {
              const int rl = wr * 64 + fr * 16 + lg * 4 + q;
              const unsigned int pos = atomicAdd(&cnt_s[rl], 1u);
              if (pos < CAND_CAP)
                cand_s[rl * CAND_CAP + pos] =
                    (unsigned short)(kcb0 + wc * 64 + fc * 16 + l15);
            }
          }
    }
  }

  __syncthreads();
  if (tid < 128) counts[rbase + tid] = cnt_s[tid];
  for (int i = tid; i < 128 * CAND_CAP; i += 256)
    cands[(size_t)rbase * CAND_CAP + i] = cand_s[i];
}

// ---------------- exact fp32 rescore + fused output/loss ----------------
// Picks exact argmin among candidates, then writes z_q_st row, idx (as float),
// and per-row loss partial. Overflow rows handled by fallback_kernel.
__global__ void rescore_kernel(const float* __restrict__ z, const float* __restrict__ cb,
                               const float* __restrict__ znorm, const float* __restrict__ enorm,
                               const unsigned int* __restrict__ counts,
                               const unsigned short* __restrict__ cands,
                               float* __restrict__ out_zq, float* __restrict__ out_idx,
                               float* __restrict__ partials) {
  const int gw  = (blockIdx.x * 256 + threadIdx.x) >> 6;
  const int ln  = threadIdx.x & 63;
  const int row = gw * 4 + (ln >> 4);
  const int ci  = ln & 15;
  const unsigned int cnt = counts[row];
  if (cnt > CAND_CAP) return;   // fallback owns this row

  const int active = ci < (int)cnt;
  const int k = active ? (int)cands[(size_t)row * CAND_CAP + ci] : 0;
  const float4* zr4 = (const float4*)(z  + (size_t)row * DIM);
  const float4* er4 = (const float4*)(cb + (size_t)k   * DIM);
  float ax = 0.f, ay = 0.f, az = 0.f, aw = 0.f;
  #pragma unroll 4
  for (int d = 0; d < DIM / 4; ++d) {
    const float4 zv = zr4[d], ev = er4[d];
    ax = fmaf(zv.x, ev.x, ax); ay = fmaf(zv.y, ev.y, ay);
    az = fmaf(zv.z, ev.z, az); aw = fmaf(zv.w, ev.w, aw);
  }
  const float dot = (ax + ay) + (az + aw);
  const float dist = fmaf(-2.0f, dot, znorm[row] + enorm[k]);
  float bv = active ? dist : FLT_MAX;
  int   bk = active ? k : 0x7fffffff;
  #pragma unroll
  for (int off = 1; off < 16; off <<= 1) {
    const float ov = __shfl_xor(bv, off);
    const int   ok = __shfl_xor(bk, off);
    if (ov < bv || (ov == bv && ok < bk)) { bv = ov; bk = ok; }
  }
  // all 16 lanes now agree on bk; fused output
  const float4* br4 = (const float4*)(cb + (size_t)bk * DIM);
  float4* o4 = (float4*)(out_zq + (size_t)row * DIM);
  float sq = 0.0f;
  #pragma unroll
  for (int t = 0; t < 4; ++t) {
    const int p = ci + 16 * t;
    const float4 zv = zr4[p], ev = br4[p];
    float4 st;
    const float dx = ev.x - zv.x, dy = ev.y - zv.y, dz = ev.z - zv.z, dw = ev.w - zv.w;
    st.x = zv.x + dx; st.y = zv.y + dy; st.z = zv.z + dz; st.w = zv.w + dw;
    o4[p] = st;
    sq += dx * dx + dy * dy + dz * dz + dw * dw;
  }
  #pragma unroll
  for (int off = 1; off < 16; off <<= 1) sq += __shfl_xor(sq, off);
  if (ci == 0) { out_idx[row] = (float)bk; partials[row] = sq; }
}

// ---------------- fallback: exact full rescan + fused output for overflow rows ----------------
__global__ void fallback_kernel(const float* __restrict__ z, const float* __restrict__ cb,
                                const float* __restrict__ znorm, const float* __restrict__ enorm,
                                const unsigned int* __restrict__ counts,
                                float* __restrict__ out_zq, float* __restrict__ out_idx,
                                float* __restrict__ partials) {
  __shared__ float bd_s[256];
  __shared__ int   bk_s[256];
  const int tid = threadIdx.x;
  for (int row = blockIdx.x; row < NROWS; row += gridDim.x) {
    if (counts[row] <= CAND_CAP) continue;   // uniform per block
    const float zn = znorm[row];
    const float* zr = z + (size_t)row * DIM;
    float bv = FLT_MAX; int bk = 0x7fffffff;
    for (int k = tid; k < KCB; k += 256) {
      const float* er = cb + (size_t)k * DIM;
      float acc = 0.0f;
      #pragma unroll 8
      for (int d = 0; d < DIM; ++d) acc = fmaf(zr[d], er[d], acc);
      const float dist = fmaf(-2.0f, acc, zn + enorm[k]);
      if (dist < bv || (dist == bv && k < bk)) { bv = dist; bk = k; }
    }
    bd_s[tid] = bv; bk_s[tid] = bk;
    __syncthreads();
    for (int s = 128; s > 0; s >>= 1) {
      if (tid < s) {
        const float ov = bd_s[tid + s]; const int ok = bk_s[tid + s];
        if (ov < bd_s[tid] || (ov == bd_s[tid] && ok < bk_s[tid])) {
          bd_s[tid] = ov; bk_s[tid] = ok;
        }
      }
      __syncthreads();
    }
    const int kb = bk_s[0];
    // fused output: 256 threads = 256 elems
    const float zv = zr[tid];
    const float ev = cb[(size_t)kb * DIM + tid];
    const float dd = ev - zv;
    out_zq[(size_t)row * DIM + tid] = zv + dd;
    if (tid == 0) out_idx[row] = (float)kb;
    __syncthreads();
    bd_s[tid] = dd * dd;
    __syncthreads();
    for (int s = 128; s > 0; s >>= 1) {
      if (tid < s) bd_s[tid] += bd_s[tid + s];
      __syncthreads();
    }
    if (tid == 0) partials[row] = bd_s[0];
    __syncthreads();
  }
}

// ---------------- loss finalize (generic count) ----------------
__global__ void loss_kernel(const float* __restrict__ partials, int n,
                            float* __restrict__ out_loss) {
  float s = 0.0f;
  for (int i = threadIdx.x; i < n; i += 256) s += partials[i];
  #pragma unroll
  for (int off = 32; off > 0; off >>= 1) s += __shfl_down(s, off);
  __shared__ float ps[4];
  if ((threadIdx.x & 63) == 0) ps[threadIdx.x >> 6] = s;
  __syncthreads();
  if (threadIdx.x == 0)
    *out_loss = 0.25f * (((ps[0] + ps[1]) + (ps[2] + ps[3])) *
                         (1.0f / (float)((size_t)NROWS * DIM)));
}

// ---------------- legacy fp32 path (round-3, used if ws too small) ----------------
__global__ void norms_kernel(const float* __restrict__ x, float* __restrict__ out) {
  const int row  = blockIdx.x * 4 + (threadIdx.x >> 6);
  const int lane = threadIdx.x & 63;
  const float4 v = ((const float4*)(x + (size_t)row * DIM))[lane];
  float s = v.x * v.x + v.y * v.y + v.z * v.z + v.w * v.w;
  #pragma unroll
  for (int off = 32; off > 0; off >>= 1) s += __shfl_down(s, off);
  if (lane == 0) out[row] = s;
}

#define BM 128
#define BK 128
#define BD 32
#define LSTR 36
__launch_bounds__(256, 2)
__global__ void argmin_kernel(const float* __restrict__ z,
                              const float* __restrict__ cb,
                              const float* __restrict__ znorm,
                              const float* __restrict__ enorm,
                              int* __restrict__ idx_out) {
  __shared__ float z_s[BM * LSTR];
  __shared__ float e_s[BK * LSTR];
  __shared__ float zn_s[BM];
  const int tid = threadIdx.x;
  const int tx = tid & 15;
  const int ty = tid >> 4;
  const int rbase = blockIdx.x * BM;
  if (tid < BM) zn_s[tid] = znorm[rbase + tid];
  float bestv[8]; int besti[8];
  #pragma unroll
  for (int i = 0; i < 8; ++i) { bestv[i] = FLT_MAX; besti[i] = 0; }
  for (int kc = 0; kc < KCB; kc += BK) {
    float acc[8][8];
    #pragma unroll
    for (int i = 0; i < 8; ++i)
      #pragma unroll
      for (int j = 0; j < 8; ++j) acc[i][j] = 0.0f;
    for (int dc = 0; dc < DIM; dc += BD) {
      __syncthreads();
      #pragma unroll
      for (int p = 0; p < 4; ++p) {
        const int el = p * 256 + tid;
        const int r  = el >> 3;
        const int c4 = (el & 7) * 4;
        *(float4*)(&z_s[r * LSTR + c4]) =
            *(const float4*)(z + (size_t)(rbase + r) * DIM + dc + c4);
        *(float4*)(&e_s[r * LSTR + c4]) =
            *(const float4*)(cb + (size_t)(kc + r) * DIM + dc + c4);
      }
      __syncthreads();
      #pragma unroll 1
      for (int dd = 0; dd < BD; dd += 4) {
        float4 b[8];
        #pragma unroll
        for (int j = 0; j < 8; ++j)
          b[j] = *(const float4*)(&e_s[(tx + 16 * j) * LSTR + dd]);
        #pragma unroll
        for (int i = 0; i < 8; ++i) {
          const float4 a = *(const float4*)(&z_s[(ty + 16 * i) * LSTR + dd]);
          #pragma unroll
          for (int j = 0; j < 8; ++j)
            acc[i][j] += a.x * b[j].x + a.y * b[j].y + a.z * b[j].z + a.w * b[j].w;
        }
      }
    }
    float en[8];
    #pragma unroll
    for (int j = 0; j < 8; ++j) en[j] = enorm[kc + tx + 16 * j];
    #pragma unroll
    for (int i = 0; i < 8; ++i) {
      const float zn = zn_s[ty + 16 * i];
      #pragma unroll
      for (int j = 0; j < 8; ++j) {
        const float t1 = zn + en[j];
        const float dist = t1 - 2.0f * acc[i][j];
        const int k = kc + tx + 16 * j;
        if (dist < bestv[i]) { bestv[i] = dist; besti[i] = k; }
      }
    }
  }
  #pragma unroll
  for (int i = 0; i < 8; ++i) {
    float lv = bestv[i]; int li = besti[i];
    #pragma unroll
    for (int off = 1; off < 16; off <<= 1) {
      const float ov = __shfl_xor(lv, off);
      const int   oi = __shfl_xor(li, off);
      if (ov < lv || (ov == lv && oi < li)) { lv = ov; li = oi; }
    }
    if (tx == 0) idx_out[rbase + ty + 16 * i] = li;
  }
}

__global__ void gather_kernel(const float* __restrict__ z,
                              const float* __restrict__ cb,
                              const int* __restrict__ idx,
                              float* __restrict__ out_zq,
                              float* __restrict__ out_idx,
                              float* __restrict__ partials) {
  const int row  = blockIdx.x * 4 + (threadIdx.x >> 6);
  const int lane = threadIdx.x & 63;
  const int k = idx[row];
  const float4 zv = ((const float4*)(z  + (size_t)row * DIM))[lane];
  const float4 ev = ((const float4*)(cb + (size_t)k   * DIM))[lane];
  float4 d, st;
  d.x = ev.x - zv.x; d.y = ev.y - zv.y; d.z = ev.z - zv.z; d.w = ev.w - zv.w;
  st.x = zv.x + d.x; st.y = zv.y + d.y; st.z = zv.z + d.z; st.w = zv.w + d.w;
  ((float4*)(out_zq + (size_t)row * DIM))[lane] = st;
  if (lane == 0) out_idx[row] = (float)k;
  float s = d.x * d.x + d.y * d.y + d.z * d.z + d.w * d.w;
  #pragma unroll
  for (int off = 32; off > 0; off >>= 1) s += __shfl_down(s, off);
  __shared__ float ps[4];
  if (lane == 0) ps[threadIdx.x >> 6] = s;
  __syncthreads();
  if (threadIdx.x == 0)
    partials[blockIdx.x] = (ps[0] + ps[1]) + (ps[2] + ps[3]);
}

extern "C" void kernel_launch(void* const* d_in, const int* in_sizes, int n_in,
                              void* d_out, int out_size, void* d_ws, size_t ws_size,
                              hipStream_t stream) {
  const float* z  = (const float*)d_in[0];   // [65536, 256]
  const float* cb = (const float*)d_in[1];   // [4096, 256]

  float* out_zq   = (float*)d_out;
  float* out_idx  = out_zq + (size_t)NROWS * DIM;
  float* out_loss = out_idx + NROWS;

  // fast-path workspace layout (bytes)
  char* w = (char*)d_ws;
  unsigned short* zh    = (unsigned short*)(w);                   // 33554432
  unsigned short* eh    = (unsigned short*)(w + 33554432);        //  2097152
  float* enorm          = (float*)(w + 35651584);                 //    16384
  float* znorm          = (float*)(w + 35667968);                 //   262144
  unsigned int* counts  = (unsigned int*)(w + 36192256);          //   262144
  unsigned short* cands = (unsigned short*)(w + 36454400);        //  2097152
  float* partials       = (float*)(w + 38551552);                 //   262144
  const size_t NEED = 38813696;

  if (ws_size >= NEED) {
    hipLaunchKernelGGL(prep_norms_kernel, dim3((NROWS + KCB) / 4), dim3(256), 0, stream,
                       z, cb, zh, eh, znorm, enorm);
    hipLaunchKernelGGL(screen_kernel, dim3(NROWS / 128), dim3(256), 0, stream,
                       zh, eh, enorm, counts, cands);
    hipLaunchKernelGGL(rescore_kernel, dim3(NROWS / 16), dim3(256), 0, stream,
                       z, cb, znorm, enorm, counts, cands, out_zq, out_idx, partials);
    hipLaunchKernelGGL(fallback_kernel, dim3(256), dim3(256), 0, stream,
                       z, cb, znorm, enorm, counts, out_zq, out_idx, partials);
    hipLaunchKernelGGL(loss_kernel, dim3(1), dim3(256), 0, stream,
                       partials, NROWS, out_loss);
  } else {
    // legacy (round-3) layout + path
    float* ws         = (float*)d_ws;
    float* enorm_l    = ws;
    float* znorm_l    = ws + KCB;
    int*   idx_l      = (int*)(ws + KCB + NROWS);
    float* partials_l = ws + KCB + 2 * NROWS;
    hipLaunchKernelGGL(norms_kernel, dim3(KCB / 4), dim3(256), 0, stream, cb, enorm_l);
    hipLaunchKernelGGL(norms_kernel, dim3(NROWS / 4), dim3(256), 0, stream, z, znorm_l);
    hipLaunchKernelGGL(argmin_kernel, dim3(NROWS / BM), dim3(256), 0, stream,
                       z, cb, znorm_l, enorm_l, idx_l);
    hipLaunchKernelGGL(gather_kernel, dim3(NROWS / 4), dim3(256), 0, stream,
                       z, cb, idx_l, out_zq, out_idx, partials_l);
    hipLaunchKernelGGL(loss_kernel, dim3(1), dim3(256), 0, stream,
                       partials_l, NROWS / 4, out_loss);
  }
}

// Round 9
// 563.251 us; speedup vs baseline: 1.2741x; 1.2741x over previous
//
#include <hip/hip_runtime.h>
#include <cfloat>

#define NROWS 65536
#define DIM   256
#define KCB   4096

#define EPS_WIN  1.8e-4f
#define CAND_CAP 16
#define SROWS    64     // rows per screen block (32 KB A tile -> 3 blocks/CU)

typedef __attribute__((ext_vector_type(8))) short short8;
typedef __attribute__((ext_vector_type(4))) float f32x4;

// ---------------- fp32 -> bf16 RNE ----------------
__device__ inline unsigned short f2bf(float x) {
  unsigned int u = __float_as_uint(x);
  return (unsigned short)((u + 0x7fffu + ((u >> 16) & 1u)) >> 16);
}

// ---------------- fused prep: bf16 convert + squared norms, one pass ----------------
__global__ void prep_norms_kernel(const float* __restrict__ z, const float* __restrict__ cb,
                                  unsigned short* __restrict__ zh, unsigned short* __restrict__ eh,
                                  float* __restrict__ znorm, float* __restrict__ enorm) {
  const int r    = blockIdx.x * 4 + (threadIdx.x >> 6);
  const int lane = threadIdx.x & 63;
  const float* src; unsigned short* dst; float* nrm; int row;
  if (r < NROWS) { src = z;  dst = zh; nrm = znorm; row = r; }
  else           { src = cb; dst = eh; nrm = enorm; row = r - NROWS; }
  const float4 v = ((const float4*)(src + (size_t)row * DIM))[lane];
  union { unsigned short us[4]; uint2 u2; } o;
  o.us[0] = f2bf(v.x); o.us[1] = f2bf(v.y); o.us[2] = f2bf(v.z); o.us[3] = f2bf(v.w);
  *(uint2*)(dst + (size_t)row * DIM + lane * 4) = o.u2;
  float s = v.x * v.x + v.y * v.y + v.z * v.z + v.w * v.w;
  #pragma unroll
  for (int off = 32; off > 0; off >>= 1) s += __shfl_down(s, off);
  if (lane == 0) nrm[row] = s;
}

// ---------------- MFMA screen: 64-row blocks, 3 blocks/CU, m97 phase shape ----------------
// Block: 64 rows x 128 codes/kt, 4 waves in 2x2 grid (wave = 32 rows x 64 cols).
// A resident in LDS 32 KB (dc-chunked 64B rows, conflict-free, gll-staged).
// Per kt: 4 phases; each phase stages 16 KB B (2 dc-chunks) via global_load_lds
// then issues 12 ds_read_b128 + 16 MFMA per wave. 9 barriers/kt.
// Screen dist is SHIFTED: s = enorm[k] - 2*dot (argmin/window shift-invariant).
__launch_bounds__(256, 3)
__global__ void screen_kernel(const unsigned short* __restrict__ zh,
                              const unsigned short* __restrict__ eh,
                              const float* __restrict__ enorm,
                              unsigned int* __restrict__ counts,
                              unsigned short* __restrict__ cands) {
  __shared__ __align__(16) unsigned short a_s[8][SROWS][32];  // 32 KB
  __shared__ __align__(16) unsigned short b_s[2][128][32];    // 16 KB
  __shared__ float tilemin_s[2][SROWS];
  __shared__ unsigned int cnt_s[SROWS];
  __shared__ unsigned short cand_s[SROWS * CAND_CAP];

  const int tid = threadIdx.x;
  const int wv  = tid >> 6;
  const int ln  = tid & 63;
  const int l15 = ln & 15;
  const int lg  = ln >> 4;
  const int wr  = wv >> 1;          // wave row-half (0/1)
  const int wc  = wv & 1;           // wave col-half (0/1)
  const int rbase = blockIdx.x * SROWS;

  if (tid < SROWS) cnt_s[tid] = 0u;

  // ---- stage A once: linear LDS dest, inverse-swizzled global source ----
  {
    const unsigned short* abase = zh + (size_t)rbase * DIM;
    unsigned short* aflat = &a_s[0][0][0];
    #pragma unroll
    for (int i = 0; i < 8; ++i) {
      const int G  = i * 256 + tid;               // 16B granule id
      const int dc = G >> 8, rem = G & 255;
      const int c  = rem >> 2, sw = rem & 3;
      const int s4 = sw ^ ((c >> 1) & 3);
      __builtin_amdgcn_global_load_lds(
          (const uint4*)(abase + (size_t)c * 256 + dc * 32 + s4 * 8),
          (uint4*)(aflat + (size_t)G * 8), 16, 0, 0);
    }
  }

  float rm[8];
  #pragma unroll
  for (int s = 0; s < 8; ++s) rm[s] = FLT_MAX;

  unsigned short* bflat = &b_s[0][0][0];

  #pragma unroll 1
  for (int kt = 0; kt < KCB / 128; ++kt) {
    const int kcb0 = kt * 128;

    f32x4 acc[2][4];
    #pragma unroll
    for (int fr = 0; fr < 2; ++fr)
      #pragma unroll
      for (int fc = 0; fc < 4; ++fc)
        acc[fr][fc] = (f32x4){0.f, 0.f, 0.f, 0.f};

    #pragma unroll 1
    for (int ph = 0; ph < 4; ++ph) {
      __syncthreads();   // prior b_s readers done (also drains A gll on 1st pass)
      // stage 2 dc-chunks of B (16 KB): 4 granules per thread
      #pragma unroll
      for (int i = 0; i < 4; ++i) {
        const int G   = i * 256 + tid;
        const int dc2 = G >> 9, rem = G & 511;
        const int c   = rem >> 2, sw = rem & 3;
        const int s4  = sw ^ ((c >> 1) & 3);
        __builtin_amdgcn_global_load_lds(
            (const uint4*)(eh + (size_t)(kcb0 + c) * 256 + (ph * 2 + dc2) * 32 + s4 * 8),
            (uint4*)(bflat + (size_t)G * 8), 16, 0, 0);
      }
      __syncthreads();   // B landed

      #pragma unroll
      for (int dc2 = 0; dc2 < 2; ++dc2) {
        const int dcg = ph * 2 + dc2;
        short8 af_[2];
        #pragma unroll
        for (int fr = 0; fr < 2; ++fr) {
          const int r  = wr * 32 + fr * 16 + l15;
          const int sl = lg ^ ((r >> 1) & 3);
          af_[fr] = *(const short8*)(&a_s[dcg][r][sl * 8]);
        }
        short8 bf[4];
        #pragma unroll
        for (int fc = 0; fc < 4; ++fc) {
          const int c  = wc * 64 + fc * 16 + l15;
          const int sw = lg ^ ((c >> 1) & 3);
          bf[fc] = *(const short8*)(&b_s[dc2][c][sw * 8]);
        }
        #pragma unroll
        for (int fr = 0; fr < 2; ++fr)
          #pragma unroll
          for (int fc = 0; fc < 4; ++fc)
            acc[fr][fc] = __builtin_amdgcn_mfma_f32_16x16x32_bf16(
                af_[fr], bf[fc], acc[fr][fc], 0, 0, 0);
      }
    }

    // ---- epilogue: shifted dist, tile-min, cross-half share, window append ----
    float en_[4];
    #pragma unroll
    for (int fc = 0; fc < 4; ++fc) en_[fc] = enorm[kcb0 + wc * 64 + fc * 16 + l15];

    float tm[8];
    #pragma unroll
    for (int s = 0; s < 8; ++s) tm[s] = FLT_MAX;

    #pragma unroll
    for (int fr = 0; fr < 2; ++fr)
      #pragma unroll
      for (int fc = 0; fc < 4; ++fc)
        #pragma unroll
        for (int q = 0; q < 4; ++q) {
          const float d_ = fmaf(-2.0f, acc[fr][fc][q], en_[fc]);
          tm[fr * 4 + q] = fminf(tm[fr * 4 + q], d_);
        }

    #pragma unroll
    for (int s = 0; s < 8; ++s) {
      float v = tm[s];
      v = fminf(v, __shfl_xor(v, 1));
      v = fminf(v, __shfl_xor(v, 2));
      v = fminf(v, __shfl_xor(v, 4));
      v = fminf(v, __shfl_xor(v, 8));
      if (l15 == 0)
        tilemin_s[wc][wr * 32 + (s >> 2) * 16 + lg * 4 + (s & 3)] = v;
    }
    __syncthreads();   // tilemin halves visible

    float gmin = FLT_MAX;
    #pragma unroll
    for (int s = 0; s < 8; ++s) {
      const int rl = wr * 32 + (s >> 2) * 16 + lg * 4 + (s & 3);
      const float comb = fminf(tilemin_s[0][rl], tilemin_s[1][rl]);
      const float m = fminf(rm[s], comb);
      rm[s] = m;
      gmin = fminf(gmin, tm[s] - m);
    }

    if (__any(gmin <= EPS_WIN)) {
      #pragma unroll
      for (int fr = 0; fr < 2; ++fr)
        #pragma unroll
        for (int fc = 0; fc < 4; ++fc)
          #pragma unroll
          for (int q = 0; q < 4; ++q) {
            const float d_ = fmaf(-2.0f, acc[fr][fc][q], en_[fc]);
            if (d_ <= rm[fr * 4 + q] + EPS_WIN) {
              const int rl = wr * 32 + fr * 16 + lg * 4 + q;
              const unsigned int pos = atomicAdd(&cnt_s[rl], 1u);
              if (pos < CAND_CAP)
                cand_s[rl * CAND_CAP + pos] =
                    (unsigned short)(kcb0 + wc * 64 + fc * 16 + l15);
            }
          }
    }
  }

  __syncthreads();
  if (tid < SROWS) counts[rbase + tid] = cnt_s[tid];
  for (int i = tid; i < SROWS * CAND_CAP; i += 256)
    cands[(size_t)rbase * CAND_CAP + i] = cand_s[i];
}

// ---------------- exact fp32 rescore + fused output/loss ----------------
__global__ void rescore_kernel(const float* __restrict__ z, const float* __restrict__ cb,
                               const float* __restrict__ znorm, const float* __restrict__ enorm,
                               const unsigned int* __restrict__ counts,
                               const unsigned short* __restrict__ cands,
                               float* __restrict__ out_zq, float* __restrict__ out_idx,
                               float* __restrict__ partials) {
  const int gw  = (blockIdx.x * 256 + threadIdx.x) >> 6;
  const int ln  = threadIdx.x & 63;
  const int row = gw * 4 + (ln >> 4);
  const int ci  = ln & 15;
  const unsigned int cnt = counts[row];
  if (cnt > CAND_CAP) return;   // fallback owns this row

  const int active = ci < (int)cnt;
  const int k = active ? (int)cands[(size_t)row * CAND_CAP + ci] : 0;
  const float4* zr4 = (const float4*)(z  + (size_t)row * DIM);
  const float4* er4 = (const float4*)(cb + (size_t)k   * DIM);
  float ax = 0.f, ay = 0.f, az = 0.f, aw = 0.f;
  #pragma unroll 4
  for (int d = 0; d < DIM / 4; ++d) {
    const float4 zv = zr4[d], ev = er4[d];
    ax = fmaf(zv.x, ev.x, ax); ay = fmaf(zv.y, ev.y, ay);
    az = fmaf(zv.z, ev.z, az); aw = fmaf(zv.w, ev.w, aw);
  }
  const float dot = (ax + ay) + (az + aw);
  const float dist = fmaf(-2.0f, dot, znorm[row] + enorm[k]);
  float bv = active ? dist : FLT_MAX;
  int   bk = active ? k : 0x7fffffff;
  #pragma unroll
  for (int off = 1; off < 16; off <<= 1) {
    const float ov = __shfl_xor(bv, off);
    const int   ok = __shfl_xor(bk, off);
    if (ov < bv || (ov == bv && ok < bk)) { bv = ov; bk = ok; }
  }
  // all 16 lanes agree on bk; fused output
  const float4* br4 = (const float4*)(cb + (size_t)bk * DIM);
  float4* o4 = (float4*)(out_zq + (size_t)row * DIM);
  float sq = 0.0f;
  #pragma unroll
  for (int t = 0; t < 4; ++t) {
    const int p = ci + 16 * t;
    const float4 zv = zr4[p], ev = br4[p];
    float4 st;
    const float dx = ev.x - zv.x, dy = ev.y - zv.y, dz = ev.z - zv.z, dw = ev.w - zv.w;
    st.x = zv.x + dx; st.y = zv.y + dy; st.z = zv.z + dz; st.w = zv.w + dw;
    o4[p] = st;
    sq += dx * dx + dy * dy + dz * dz + dw * dw;
  }
  #pragma unroll
  for (int off = 1; off < 16; off <<= 1) sq += __shfl_xor(sq, off);
  if (ci == 0) { out_idx[row] = (float)bk; partials[row] = sq; }
}

// ---------------- fallback: exact full rescan + fused output for overflow rows ----------------
__global__ void fallback_kernel(const float* __restrict__ z, const float* __restrict__ cb,
                                const float* __restrict__ znorm, const float* __restrict__ enorm,
                                const unsigned int* __restrict__ counts,
                                float* __restrict__ out_zq, float* __restrict__ out_idx,
                                float* __restrict__ partials) {
  __shared__ float bd_s[256];
  __shared__ int   bk_s[256];
  const int tid = threadIdx.x;
  for (int row = blockIdx.x; row < NROWS; row += gridDim.x) {
    if (counts[row] <= CAND_CAP) continue;   // uniform per block
    const float zn = znorm[row];
    const float* zr = z + (size_t)row * DIM;
    float bv = FLT_MAX; int bk = 0x7fffffff;
    for (int k = tid; k < KCB; k += 256) {
      const float* er = cb + (size_t)k * DIM;
      float acc = 0.0f;
      #pragma unroll 8
      for (int d = 0; d < DIM; ++d) acc = fmaf(zr[d], er[d], acc);
      const float dist = fmaf(-2.0f, acc, zn + enorm[k]);
      if (dist < bv || (dist == bv && k < bk)) { bv = dist; bk = k; }
    }
    bd_s[tid] = bv; bk_s[tid] = bk;
    __syncthreads();
    for (int s = 128; s > 0; s >>= 1) {
      if (tid < s) {
        const float ov = bd_s[tid + s]; const int ok = bk_s[tid + s];
        if (ov < bd_s[tid] || (ov == bd_s[tid] && ok < bk_s[tid])) {
          bd_s[tid] = ov; bk_s[tid] = ok;
        }
      }
      __syncthreads();
    }
    const int kb = bk_s[0];
    const float zv = zr[tid];
    const float ev = cb[(size_t)kb * DIM + tid];
    const float dd = ev - zv;
    out_zq[(size_t)row * DIM + tid] = zv + dd;
    if (tid == 0) out_idx[row] = (float)kb;
    __syncthreads();
    bd_s[tid] = dd * dd;
    __syncthreads();
    for (int s = 128; s > 0; s >>= 1) {
      if (tid < s) bd_s[tid] += bd_s[tid + s];
      __syncthreads();
    }
    if (tid == 0) partials[row] = bd_s[0];
    __syncthreads();
  }
}

// ---------------- loss finalize (generic count) ----------------
__global__ void loss_kernel(const float* __restrict__ partials, int n,
                            float* __restrict__ out_loss) {
  float s = 0.0f;
  for (int i = threadIdx.x; i < n; i += 256) s += partials[i];
  #pragma unroll
  for (int off = 32; off > 0; off >>= 1) s += __shfl_down(s, off);
  __shared__ float ps[4];
  if ((threadIdx.x & 63) == 0) ps[threadIdx.x >> 6] = s;
  __syncthreads();
  if (threadIdx.x == 0)
    *out_loss = 0.25f * (((ps[0] + ps[1]) + (ps[2] + ps[3])) *
                         (1.0f / (float)((size_t)NROWS * DIM)));
}

// ---------------- legacy fp32 path (round-3, used if ws too small) ----------------
__global__ void norms_kernel(const float* __restrict__ x, float* __restrict__ out) {
  const int row  = blockIdx.x * 4 + (threadIdx.x >> 6);
  const int lane = threadIdx.x & 63;
  const float4 v = ((const float4*)(x + (size_t)row * DIM))[lane];
  float s = v.x * v.x + v.y * v.y + v.z * v.z + v.w * v.w;
  #pragma unroll
  for (int off = 32; off > 0; off >>= 1) s += __shfl_down(s, off);
  if (lane == 0) out[row] = s;
}

#define BM 128
#define BK 128
#define BD 32
#define LSTR 36
__launch_bounds__(256, 2)
__global__ void argmin_kernel(const float* __restrict__ z,
                              const float* __restrict__ cb,
                              const float* __restrict__ znorm,
                              const float* __restrict__ enorm,
                              int* __restrict__ idx_out) {
  __shared__ float z_s[BM * LSTR];
  __shared__ float e_s[BK * LSTR];
  __shared__ float zn_s[BM];
  const int tid = threadIdx.x;
  const int tx = tid & 15;
  const int ty = tid >> 4;
  const int rbase = blockIdx.x * BM;
  if (tid < BM) zn_s[tid] = znorm[rbase + tid];
  float bestv[8]; int besti[8];
  #pragma unroll
  for (int i = 0; i < 8; ++i) { bestv[i] = FLT_MAX; besti[i] = 0; }
  for (int kc = 0; kc < KCB; kc += BK) {
    float acc[8][8];
    #pragma unroll
    for (int i = 0; i < 8; ++i)
      #pragma unroll
      for (int j = 0; j < 8; ++j) acc[i][j] = 0.0f;
    for (int dc = 0; dc < DIM; dc += BD) {
      __syncthreads();
      #pragma unroll
      for (int p = 0; p < 4; ++p) {
        const int el = p * 256 + tid;
        const int r  = el >> 3;
        const int c4 = (el & 7) * 4;
        *(float4*)(&z_s[r * LSTR + c4]) =
            *(const float4*)(z + (size_t)(rbase + r) * DIM + dc + c4);
        *(float4*)(&e_s[r * LSTR + c4]) =
            *(const float4*)(cb + (size_t)(kc + r) * DIM + dc + c4);
      }
      __syncthreads();
      #pragma unroll 1
      for (int dd = 0; dd < BD; dd += 4) {
        float4 b[8];
        #pragma unroll
        for (int j = 0; j < 8; ++j)
          b[j] = *(const float4*)(&e_s[(tx + 16 * j) * LSTR + dd]);
        #pragma unroll
        for (int i = 0; i < 8; ++i) {
          const float4 a = *(const float4*)(&z_s[(ty + 16 * i) * LSTR + dd]);
          #pragma unroll
          for (int j = 0; j < 8; ++j)
            acc[i][j] += a.x * b[j].x + a.y * b[j].y + a.z * b[j].z + a.w * b[j].w;
        }
      }
    }
    float en[8];
    #pragma unroll
    for (int j = 0; j < 8; ++j) en[j] = enorm[kc + tx + 16 * j];
    #pragma unroll
    for (int i = 0; i < 8; ++i) {
      const float zn = zn_s[ty + 16 * i];
      #pragma unroll
      for (int j = 0; j < 8; ++j) {
        const float t1 = zn + en[j];
        const float dist = t1 - 2.0f * acc[i][j];
        const int k = kc + tx + 16 * j;
        if (dist < bestv[i]) { bestv[i] = dist; besti[i] = k; }
      }
    }
  }
  #pragma unroll
  for (int i = 0; i < 8; ++i) {
    float lv = bestv[i]; int li = besti[i];
    #pragma unroll
    for (int off = 1; off < 16; off <<= 1) {
      const float ov = __shfl_xor(lv, off);
      const int   oi = __shfl_xor(li, off);
      if (ov < lv || (ov == lv && oi < li)) { lv = ov; li = oi; }
    }
    if (tx == 0) idx_out[rbase + ty + 16 * i] = li;
  }
}

__global__ void gather_kernel(const float* __restrict__ z,
                              const float* __restrict__ cb,
                              const int* __restrict__ idx,
                              float* __restrict__ out_zq,
                              float* __restrict__ out_idx,
                              float* __restrict__ partials) {
  const int row  = blockIdx.x * 4 + (threadIdx.x >> 6);
  const int lane = threadIdx.x & 63;
  const int k = idx[row];
  const float4 zv = ((const float4*)(z  + (size_t)row * DIM))[lane];
  const float4 ev = ((const float4*)(cb + (size_t)k   * DIM))[lane];
  float4 d, st;
  d.x = ev.x - zv.x; d.y = ev.y - zv.y; d.z = ev.z - zv.z; d.w = ev.w - zv.w;
  st.x = zv.x + d.x; st.y = zv.y + d.y; st.z = zv.z + d.z; st.w = zv.w + d.w;
  ((float4*)(out_zq + (size_t)row * DIM))[lane] = st;
  if (lane == 0) out_idx[row] = (float)k;
  float s = d.x * d.x + d.y * d.y + d.z * d.z + d.w * d.w;
  #pragma unroll
  for (int off = 32; off > 0; off >>= 1) s += __shfl_down(s, off);
  __shared__ float ps[4];
  if (lane == 0) ps[threadIdx.x >> 6] = s;
  __syncthreads();
  if (threadIdx.x == 0)
    partials[blockIdx.x] = (ps[0] + ps[1]) + (ps[2] + ps[3]);
}

extern "C" void kernel_launch(void* const* d_in, const int* in_sizes, int n_in,
                              void* d_out, int out_size, void* d_ws, size_t ws_size,
                              hipStream_t stream) {
  const float* z  = (const float*)d_in[0];   // [65536, 256]
  const float* cb = (const float*)d_in[1];   // [4096, 256]

  float* out_zq   = (float*)d_out;
  float* out_idx  = out_zq + (size_t)NROWS * DIM;
  float* out_loss = out_idx + NROWS;

  // fast-path workspace layout (bytes)
  char* w = (char*)d_ws;
  unsigned short* zh    = (unsigned short*)(w);                   // 33554432
  unsigned short* eh    = (unsigned short*)(w + 33554432);        //  2097152
  float* enorm          = (float*)(w + 35651584);                 //    16384
  float* znorm          = (float*)(w + 35667968);                 //   262144
  unsigned int* counts  = (unsigned int*)(w + 36192256);          //   262144
  unsigned short* cands = (unsigned short*)(w + 36454400);        //  2097152
  float* partials       = (float*)(w + 38551552);                 //   262144
  const size_t NEED = 38813696;

  if (ws_size >= NEED) {
    hipLaunchKernelGGL(prep_norms_kernel, dim3((NROWS + KCB) / 4), dim3(256), 0, stream,
                       z, cb, zh, eh, znorm, enorm);
    hipLaunchKernelGGL(screen_kernel, dim3(NROWS / SROWS), dim3(256), 0, stream,
                       zh, eh, enorm, counts, cands);
    hipLaunchKernelGGL(rescore_kernel, dim3(NROWS / 16), dim3(256), 0, stream,
                       z, cb, znorm, enorm, counts, cands, out_zq, out_idx, partials);
    hipLaunchKernelGGL(fallback_kernel, dim3(256), dim3(256), 0, stream,
                       z, cb, znorm, enorm, counts, out_zq, out_idx, partials);
    hipLaunchKernelGGL(loss_kernel, dim3(1), dim3(256), 0, stream,
                       partials, NROWS, out_loss);
  } else {
    // legacy (round-3) layout + path
    float* ws         = (float*)d_ws;
    float* enorm_l    = ws;
    float* znorm_l    = ws + KCB;
    int*   idx_l      = (int*)(ws + KCB + NROWS);
    float* partials_l = ws + KCB + 2 * NROWS;
    hipLaunchKernelGGL(norms_kernel, dim3(KCB / 4), dim3(256), 0, stream, cb, enorm_l);
    hipLaunchKernelGGL(norms_kernel, dim3(NROWS / 4), dim3(256), 0, stream, z, znorm_l);
    hipLaunchKernelGGL(argmin_kernel, dim3(NROWS / BM), dim3(256), 0, stream,
                       z, cb, znorm_l, enorm_l, idx_l);
    hipLaunchKernelGGL(gather_kernel, dim3(NROWS / 4), dim3(256), 0, stream,
                       z, cb, idx_l, out_zq, out_idx, partials_l);
    hipLaunchKernelGGL(loss_kernel, dim3(1), dim3(256), 0, stream,
                       partials_l, NROWS / 4, out_loss);
  }
}

// Round 10
// 547.182 us; speedup vs baseline: 1.3115x; 1.0294x over previous
//
#include <hip/hip_runtime.h>
#include <cfloat>

#define NROWS 65536
#define DIM   256
#define KCB   4096

#define EPS_WIN  1.8e-4f
#define CAND_CAP 16
#define SROWS    64     // rows per screen block (32 KB A tile -> 3 blocks/CU)

typedef __attribute__((ext_vector_type(8))) short short8;
typedef __attribute__((ext_vector_type(4))) float f32x4;

// ---------------- fp32 -> bf16 RNE ----------------
__device__ inline unsigned short f2bf(float x) {
  unsigned int u = __float_as_uint(x);
  return (unsigned short)((u + 0x7fffu + ((u >> 16) & 1u)) >> 16);
}

// ---------------- fused prep: bf16 convert + squared norms, one pass ----------------
__global__ void prep_norms_kernel(const float* __restrict__ z, const float* __restrict__ cb,
                                  unsigned short* __restrict__ zh, unsigned short* __restrict__ eh,
                                  float* __restrict__ znorm, float* __restrict__ enorm) {
  const int r    = blockIdx.x * 4 + (threadIdx.x >> 6);
  const int lane = threadIdx.x & 63;
  const float* src; unsigned short* dst; float* nrm; int row;
  if (r < NROWS) { src = z;  dst = zh; nrm = znorm; row = r; }
  else           { src = cb; dst = eh; nrm = enorm; row = r - NROWS; }
  const float4 v = ((const float4*)(src + (size_t)row * DIM))[lane];
  union { unsigned short us[4]; uint2 u2; } o;
  o.us[0] = f2bf(v.x); o.us[1] = f2bf(v.y); o.us[2] = f2bf(v.z); o.us[3] = f2bf(v.w);
  *(uint2*)(dst + (size_t)row * DIM + lane * 4) = o.u2;
  float s = v.x * v.x + v.y * v.y + v.z * v.z + v.w * v.w;
  #pragma unroll
  for (int off = 32; off > 0; off >>= 1) s += __shfl_down(s, off);
  if (lane == 0) nrm[row] = s;
}

// ---------------- MFMA screen: 2-phase pipelined, full-width waves ----------------
// Block: 64 rows, 4 waves; wave = 16 rows x 128 cols (1 A-frag x 8 B-frags).
// A resident in LDS 32 KB (dc-chunked 64B rows, conflict-free, gll-staged).
// B double-buffered 2x8 KB. Per chunk (kt,dc): issue next chunk's
// global_load_lds into buf[cur^1], ds_read+8 MFMA on buf[cur], ONE barrier
// (drains the in-flight stage that had the whole compute phase to fly).
// Epilogue per kt is barrier-free (intra-wave shuffles only).
// Screen dist is SHIFTED: s = enorm[k] - 2*dot (argmin/window shift-invariant).
__launch_bounds__(256, 3)
__global__ void screen_kernel(const unsigned short* __restrict__ zh,
                              const unsigned short* __restrict__ eh,
                              const float* __restrict__ enorm,
                              unsigned int* __restrict__ counts,
                              unsigned short* __restrict__ cands) {
  __shared__ __align__(16) unsigned short a_s[8][SROWS][32];  // 32 KB
  __shared__ __align__(16) unsigned short b_s[2][128][32];    // 2 x 8 KB
  __shared__ unsigned int cnt_s[SROWS];
  __shared__ unsigned short cand_s[SROWS * CAND_CAP];

  const int tid = threadIdx.x;
  const int wv  = tid >> 6;
  const int ln  = tid & 63;
  const int l15 = ln & 15;
  const int lg  = ln >> 4;
  const int rbase = blockIdx.x * SROWS;

  if (tid < SROWS) cnt_s[tid] = 0u;

  // ---- issue A staging (32 KB) + B chunk 0 (8 KB); one drain barrier ----
  {
    const unsigned short* abase = zh + (size_t)rbase * DIM;
    unsigned short* aflat = &a_s[0][0][0];
    #pragma unroll
    for (int i = 0; i < 8; ++i) {
      const int G  = i * 256 + tid;               // 16B granule id
      const int dc = G >> 8, rem = G & 255;
      const int c  = rem >> 2, sw = rem & 3;
      const int s4 = sw ^ ((c >> 1) & 3);
      __builtin_amdgcn_global_load_lds(
          (const uint4*)(abase + (size_t)c * 256 + dc * 32 + s4 * 8),
          (uint4*)(aflat + (size_t)G * 8), 16, 0, 0);
    }
    unsigned short* b0 = &b_s[0][0][0];
    #pragma unroll
    for (int i = 0; i < 2; ++i) {
      const int G  = i * 256 + tid;
      const int c  = G >> 2, sw = G & 3;
      const int s4 = sw ^ ((c >> 1) & 3);
      __builtin_amdgcn_global_load_lds(
          (const uint4*)(eh + (size_t)c * 256 + s4 * 8),
          (uint4*)(b0 + (size_t)G * 8), 16, 0, 0);
    }
  }
  __syncthreads();

  // A-frag LDS address pieces (constant per thread)
  const int ar = l15;                 // row within wave's 16 = l15
  const int arow = wv * 16 + ar;      // row within block
  const int asl = lg ^ ((arow >> 1) & 3);

  float rm[4];
  #pragma unroll
  for (int q = 0; q < 4; ++q) rm[q] = FLT_MAX;

  int cur = 0;

  #pragma unroll 1
  for (int kt = 0; kt < KCB / 128; ++kt) {
    const int kcb0 = kt * 128;

    f32x4 acc[8];
    #pragma unroll
    for (int fc = 0; fc < 8; ++fc) acc[fc] = (f32x4){0.f, 0.f, 0.f, 0.f};

    #pragma unroll 1
    for (int dc = 0; dc < 8; ++dc) {
      // ---- issue NEXT chunk's stage into buf[cur^1] (wraps at end: benign) ----
      {
        const int t   = (kt * 8 + dc + 1) & 255;
        const int nkt = t >> 3, ndc = t & 7;
        unsigned short* bn = &b_s[cur ^ 1][0][0];
        #pragma unroll
        for (int i = 0; i < 2; ++i) {
          const int G  = i * 256 + tid;
          const int c  = G >> 2, sw = G & 3;
          const int s4 = sw ^ ((c >> 1) & 3);
          __builtin_amdgcn_global_load_lds(
              (const uint4*)(eh + (size_t)(nkt * 128 + c) * 256 + ndc * 32 + s4 * 8),
              (uint4*)(bn + (size_t)G * 8), 16, 0, 0);
        }
      }

      // ---- compute on buf[cur] ----
      const short8 af = *(const short8*)(&a_s[dc][arow][asl * 8]);
      short8 bf[8];
      #pragma unroll
      for (int fc = 0; fc < 8; ++fc) {
        const int c  = fc * 16 + l15;
        const int sw = lg ^ ((c >> 1) & 3);
        bf[fc] = *(const short8*)(&b_s[cur][c][sw * 8]);
      }
      #pragma unroll
      for (int fc = 0; fc < 8; ++fc)
        acc[fc] = __builtin_amdgcn_mfma_f32_16x16x32_bf16(af, bf[fc], acc[fc], 0, 0, 0);

      __syncthreads();   // next stage landed; cur's readers done before overwrite
      cur ^= 1;
    }

    // ---- epilogue (barrier-free): shifted dist, row tile-min, window append ----
    float en_[8];
    #pragma unroll
    for (int fc = 0; fc < 8; ++fc) en_[fc] = enorm[kcb0 + fc * 16 + l15];

    float tm[4];
    #pragma unroll
    for (int q = 0; q < 4; ++q) tm[q] = FLT_MAX;

    #pragma unroll
    for (int fc = 0; fc < 8; ++fc)
      #pragma unroll
      for (int q = 0; q < 4; ++q) {
        const float d_ = fmaf(-2.0f, acc[fc][q], en_[fc]);
        tm[q] = fminf(tm[q], d_);
      }

    float gmin = FLT_MAX;
    #pragma unroll
    for (int q = 0; q < 4; ++q) {
      float v = tm[q];                 // reduce over the 16 l15 lanes (bits 0-3)
      v = fminf(v, __shfl_xor(v, 1));
      v = fminf(v, __shfl_xor(v, 2));
      v = fminf(v, __shfl_xor(v, 4));
      v = fminf(v, __shfl_xor(v, 8));
      const float m = fminf(rm[q], v);
      rm[q] = m;
      gmin = fminf(gmin, tm[q] - m);
    }

    if (__any(gmin <= EPS_WIN)) {
      #pragma unroll
      for (int fc = 0; fc < 8; ++fc)
        #pragma unroll
        for (int q = 0; q < 4; ++q) {
          const float d_ = fmaf(-2.0f, acc[fc][q], en_[fc]);
          if (d_ <= rm[q] + EPS_WIN) {
            const int rl = wv * 16 + lg * 4 + q;
            const unsigned int pos = atomicAdd(&cnt_s[rl], 1u);
            if (pos < CAND_CAP)
              cand_s[rl * CAND_CAP + pos] =
                  (unsigned short)(kcb0 + fc * 16 + l15);
          }
        }
    }
  }

  __syncthreads();
  if (tid < SROWS) counts[rbase + tid] = cnt_s[tid];
  for (int i = tid; i < SROWS * CAND_CAP; i += 256)
    cands[(size_t)rbase * CAND_CAP + i] = cand_s[i];
}

// ---------------- exact fp32 rescore + fused output/loss ----------------
__global__ void rescore_kernel(const float* __restrict__ z, const float* __restrict__ cb,
                               const float* __restrict__ znorm, const float* __restrict__ enorm,
                               const unsigned int* __restrict__ counts,
                               const unsigned short* __restrict__ cands,
                               float* __restrict__ out_zq, float* __restrict__ out_idx,
                               float* __restrict__ partials) {
  const int gw  = (blockIdx.x * 256 + threadIdx.x) >> 6;
  const int ln  = threadIdx.x & 63;
  const int row = gw * 4 + (ln >> 4);
  const int ci  = ln & 15;
  const unsigned int cnt = counts[row];
  if (cnt > CAND_CAP) return;   // fallback owns this row

  const int active = ci < (int)cnt;
  const int k = active ? (int)cands[(size_t)row * CAND_CAP + ci] : 0;
  const float4* zr4 = (const float4*)(z  + (size_t)row * DIM);
  const float4* er4 = (const float4*)(cb + (size_t)k   * DIM);
  float ax = 0.f, ay = 0.f, az = 0.f, aw = 0.f;
  #pragma unroll 4
  for (int d = 0; d < DIM / 4; ++d) {
    const float4 zv = zr4[d], ev = er4[d];
    ax = fmaf(zv.x, ev.x, ax); ay = fmaf(zv.y, ev.y, ay);
    az = fmaf(zv.z, ev.z, az); aw = fmaf(zv.w, ev.w, aw);
  }
  const float dot = (ax + ay) + (az + aw);
  const float dist = fmaf(-2.0f, dot, znorm[row] + enorm[k]);
  float bv = active ? dist : FLT_MAX;
  int   bk = active ? k : 0x7fffffff;
  #pragma unroll
  for (int off = 1; off < 16; off <<= 1) {
    const float ov = __shfl_xor(bv, off);
    const int   ok = __shfl_xor(bk, off);
    if (ov < bv || (ov == bv && ok < bk)) { bv = ov; bk = ok; }
  }
  // all 16 lanes agree on bk; fused output
  const float4* br4 = (const float4*)(cb + (size_t)bk * DIM);
  float4* o4 = (float4*)(out_zq + (size_t)row * DIM);
  float sq = 0.0f;
  #pragma unroll
  for (int t = 0; t < 4; ++t) {
    const int p = ci + 16 * t;
    const float4 zv = zr4[p], ev = br4[p];
    float4 st;
    const float dx = ev.x - zv.x, dy = ev.y - zv.y, dz = ev.z - zv.z, dw = ev.w - zv.w;
    st.x = zv.x + dx; st.y = zv.y + dy; st.z = zv.z + dz; st.w = zv.w + dw;
    o4[p] = st;
    sq += dx * dx + dy * dy + dz * dz + dw * dw;
  }
  #pragma unroll
  for (int off = 1; off < 16; off <<= 1) sq += __shfl_xor(sq, off);
  if (ci == 0) { out_idx[row] = (float)bk; partials[row] = sq; }
}

// ---------------- fallback: exact full rescan + fused output for overflow rows ----------------
__global__ void fallback_kernel(const float* __restrict__ z, const float* __restrict__ cb,
                                const float* __restrict__ znorm, const float* __restrict__ enorm,
                                const unsigned int* __restrict__ counts,
                                float* __restrict__ out_zq, float* __restrict__ out_idx,
                                float* __restrict__ partials) {
  __shared__ float bd_s[256];
  __shared__ int   bk_s[256];
  const int tid = threadIdx.x;
  for (int row = blockIdx.x; row < NROWS; row += gridDim.x) {
    if (counts[row] <= CAND_CAP) continue;   // uniform per block
    const float zn = znorm[row];
    const float* zr = z + (size_t)row * DIM;
    float bv = FLT_MAX; int bk = 0x7fffffff;
    for (int k = tid; k < KCB; k += 256) {
      const float* er = cb + (size_t)k * DIM;
      float acc = 0.0f;
      #pragma unroll 8
      for (int d = 0; d < DIM; ++d) acc = fmaf(zr[d], er[d], acc);
      const float dist = fmaf(-2.0f, acc, zn + enorm[k]);
      if (dist < bv || (dist == bv && k < bk)) { bv = dist; bk = k; }
    }
    bd_s[tid] = bv; bk_s[tid] = bk;
    __syncthreads();
    for (int s = 128; s > 0; s >>= 1) {
      if (tid < s) {
        const float ov = bd_s[tid + s]; const int ok = bk_s[tid + s];
        if (ov < bd_s[tid] || (ov == bd_s[tid] && ok < bk_s[tid])) {
          bd_s[tid] = ov; bk_s[tid] = ok;
        }
      }
      __syncthreads();
    }
    const int kb = bk_s[0];
    const float zv = zr[tid];
    const float ev = cb[(size_t)kb * DIM + tid];
    const float dd = ev - zv;
    out_zq[(size_t)row * DIM + tid] = zv + dd;
    if (tid == 0) out_idx[row] = (float)kb;
    __syncthreads();
    bd_s[tid] = dd * dd;
    __syncthreads();
    for (int s = 128; s > 0; s >>= 1) {
      if (tid < s) bd_s[tid] += bd_s[tid + s];
      __syncthreads();
    }
    if (tid == 0) partials[row] = bd_s[0];
    __syncthreads();
  }
}

// ---------------- loss finalize (generic count) ----------------
__global__ void loss_kernel(const float* __restrict__ partials, int n,
                            float* __restrict__ out_loss) {
  float s = 0.0f;
  for (int i = threadIdx.x; i < n; i += 256) s += partials[i];
  #pragma unroll
  for (int off = 32; off > 0; off >>= 1) s += __shfl_down(s, off);
  __shared__ float ps[4];
  if ((threadIdx.x & 63) == 0) ps[threadIdx.x >> 6] = s;
  __syncthreads();
  if (threadIdx.x == 0)
    *out_loss = 0.25f * (((ps[0] + ps[1]) + (ps[2] + ps[3])) *
                         (1.0f / (float)((size_t)NROWS * DIM)));
}

// ---------------- legacy fp32 path (round-3, used if ws too small) ----------------
__global__ void norms_kernel(const float* __restrict__ x, float* __restrict__ out) {
  const int row  = blockIdx.x * 4 + (threadIdx.x >> 6);
  const int lane = threadIdx.x & 63;
  const float4 v = ((const float4*)(x + (size_t)row * DIM))[lane];
  float s = v.x * v.x + v.y * v.y + v.z * v.z + v.w * v.w;
  #pragma unroll
  for (int off = 32; off > 0; off >>= 1) s += __shfl_down(s, off);
  if (lane == 0) out[row] = s;
}

#define BM 128
#define BK 128
#define BD 32
#define LSTR 36
__launch_bounds__(256, 2)
__global__ void argmin_kernel(const float* __restrict__ z,
                              const float* __restrict__ cb,
                              const float* __restrict__ znorm,
                              const float* __restrict__ enorm,
                              int* __restrict__ idx_out) {
  __shared__ float z_s[BM * LSTR];
  __shared__ float e_s[BK * LSTR];
  __shared__ float zn_s[BM];
  const int tid = threadIdx.x;
  const int tx = tid & 15;
  const int ty = tid >> 4;
  const int rbase = blockIdx.x * BM;
  if (tid < BM) zn_s[tid] = znorm[rbase + tid];
  float bestv[8]; int besti[8];
  #pragma unroll
  for (int i = 0; i < 8; ++i) { bestv[i] = FLT_MAX; besti[i] = 0; }
  for (int kc = 0; kc < KCB; kc += BK) {
    float acc[8][8];
    #pragma unroll
    for (int i = 0; i < 8; ++i)
      #pragma unroll
      for (int j = 0; j < 8; ++j) acc[i][j] = 0.0f;
    for (int dc = 0; dc < DIM; dc += BD) {
      __syncthreads();
      #pragma unroll
      for (int p = 0; p < 4; ++p) {
        const int el = p * 256 + tid;
        const int r  = el >> 3;
        const int c4 = (el & 7) * 4;
        *(float4*)(&z_s[r * LSTR + c4]) =
            *(const float4*)(z + (size_t)(rbase + r) * DIM + dc + c4);
        *(float4*)(&e_s[r * LSTR + c4]) =
            *(const float4*)(cb + (size_t)(kc + r) * DIM + dc + c4);
      }
      __syncthreads();
      #pragma unroll 1
      for (int dd = 0; dd < BD; dd += 4) {
        float4 b[8];
        #pragma unroll
        for (int j = 0; j < 8; ++j)
          b[j] = *(const float4*)(&e_s[(tx + 16 * j) * LSTR + dd]);
        #pragma unroll
        for (int i = 0; i < 8; ++i) {
          const float4 a = *(const float4*)(&z_s[(ty + 16 * i) * LSTR + dd]);
          #pragma unroll
          for (int j = 0; j < 8; ++j)
            acc[i][j] += a.x * b[j].x + a.y * b[j].y + a.z * b[j].z + a.w * b[j].w;
        }
      }
    }
    float en[8];
    #pragma unroll
    for (int j = 0; j < 8; ++j) en[j] = enorm[kc + tx + 16 * j];
    #pragma unroll
    for (int i = 0; i < 8; ++i) {
      const float zn = zn_s[ty + 16 * i];
      #pragma unroll
      for (int j = 0; j < 8; ++j) {
        const float t1 = zn + en[j];
        const float dist = t1 - 2.0f * acc[i][j];
        const int k = kc + tx + 16 * j;
        if (dist < bestv[i]) { bestv[i] = dist; besti[i] = k; }
      }
    }
  }
  #pragma unroll
  for (int i = 0; i < 8; ++i) {
    float lv = bestv[i]; int li = besti[i];
    #pragma unroll
    for (int off = 1; off < 16; off <<= 1) {
      const float ov = __shfl_xor(lv, off);
      const int   oi = __shfl_xor(li, off);
      if (ov < lv || (ov == lv && oi < li)) { lv = ov; li = oi; }
    }
    if (tx == 0) idx_out[rbase + ty + 16 * i] = li;
  }
}

__global__ void gather_kernel(const float* __restrict__ z,
                              const float* __restrict__ cb,
                              const int* __restrict__ idx,
                              float* __restrict__ out_zq,
                              float* __restrict__ out_idx,
                              float* __restrict__ partials) {
  const int row  = blockIdx.x * 4 + (threadIdx.x >> 6);
  const int lane = threadIdx.x & 63;
  const int k = idx[row];
  const float4 zv = ((const float4*)(z  + (size_t)row * DIM))[lane];
  const float4 ev = ((const float4*)(cb + (size_t)k   * DIM))[lane];
  float4 d, st;
  d.x = ev.x - zv.x; d.y = ev.y - zv.y; d.z = ev.z - zv.z; d.w = ev.w - zv.w;
  st.x = zv.x + d.x; st.y = zv.y + d.y; st.z = zv.z + d.z; st.w = zv.w + d.w;
  ((float4*)(out_zq + (size_t)row * DIM))[lane] = st;
  if (lane == 0) out_idx[row] = (float)k;
  float s = d.x * d.x + d.y * d.y + d.z * d.z + d.w * d.w;
  #pragma unroll
  for (int off = 32; off > 0; off >>= 1) s += __shfl_down(s, off);
  __shared__ float ps[4];
  if (lane == 0) ps[threadIdx.x >> 6] = s;
  __syncthreads();
  if (threadIdx.x == 0)
    partials[blockIdx.x] = (ps[0] + ps[1]) + (ps[2] + ps[3]);
}

extern "C" void kernel_launch(void* const* d_in, const int* in_sizes, int n_in,
                              void* d_out, int out_size, void* d_ws, size_t ws_size,
                              hipStream_t stream) {
  const float* z  = (const float*)d_in[0];   // [65536, 256]
  const float* cb = (const float*)d_in[1];   // [4096, 256]

  float* out_zq   = (float*)d_out;
  float* out_idx  = out_zq + (size_t)NROWS * DIM;
  float* out_loss = out_idx + NROWS;

  // fast-path workspace layout (bytes)
  char* w = (char*)d_ws;
  unsigned short* zh    = (unsigned short*)(w);                   // 33554432
  unsigned short* eh    = (unsigned short*)(w + 33554432);        //  2097152
  float* enorm          = (float*)(w + 35651584);                 //    16384
  float* znorm          = (float*)(w + 35667968);                 //   262144
  unsigned int* counts  = (unsigned int*)(w + 36192256);          //   262144
  unsigned short* cands = (unsigned short*)(w + 36454400);        //  2097152
  float* partials       = (float*)(w + 38551552);                 //   262144
  const size_t NEED = 38813696;

  if (ws_size >= NEED) {
    hipLaunchKernelGGL(prep_norms_kernel, dim3((NROWS + KCB) / 4), dim3(256), 0, stream,
                       z, cb, zh, eh, znorm, enorm);
    hipLaunchKernelGGL(screen_kernel, dim3(NROWS / SROWS), dim3(256), 0, stream,
                       zh, eh, enorm, counts, cands);
    hipLaunchKernelGGL(rescore_kernel, dim3(NROWS / 16), dim3(256), 0, stream,
                       z, cb, znorm, enorm, counts, cands, out_zq, out_idx, partials);
    hipLaunchKernelGGL(fallback_kernel, dim3(256), dim3(256), 0, stream,
                       z, cb, znorm, enorm, counts, out_zq, out_idx, partials);
    hipLaunchKernelGGL(loss_kernel, dim3(1), dim3(256), 0, stream,
                       partials, NROWS, out_loss);
  } else {
    // legacy (round-3) layout + path
    float* ws         = (float*)d_ws;
    float* enorm_l    = ws;
    float* znorm_l    = ws + KCB;
    int*   idx_l      = (int*)(ws + KCB + NROWS);
    float* partials_l = ws + KCB + 2 * NROWS;
    hipLaunchKernelGGL(norms_kernel, dim3(KCB / 4), dim3(256), 0, stream, cb, enorm_l);
    hipLaunchKernelGGL(norms_kernel, dim3(NROWS / 4), dim3(256), 0, stream, z, znorm_l);
    hipLaunchKernelGGL(argmin_kernel, dim3(NROWS / BM), dim3(256), 0, stream,
                       z, cb, znorm_l, enorm_l, idx_l);
    hipLaunchKernelGGL(gather_kernel, dim3(NROWS / 4), dim3(256), 0, stream,
                       z, cb, idx_l, out_zq, out_idx, partials_l);
    hipLaunchKernelGGL(loss_kernel, dim3(1), dim3(256), 0, stream,
                       partials_l, NROWS / 4, out_loss);
  }
}